// Round 9
// baseline (89.177 us; speedup 1.0000x reference)
//
#include <hip/hip_runtime.h>

// Problem constants (fixed by the reference setup)
#define Bc   2
#define Cc   256
#define Hc   80
#define Wc   160
#define Gc   4
#define Sc   9
#define GCc  64              // channels per group
#define HWc  (Hc * Wc)
#define H2c  (Hc / 2)        // 40 row-pair tiles
#define WTc  (Wc / 32)       // 5 col tiles of 32
#define NW   2               // waves per block
#define CPW  32              // channels per wave

// fp16 vertical-pair tile: dword (t,x) = fp16x2(v(minY+t,x), v(minY+t+1,x)).
// Double-buffered SHIFTED pipeline (R9): compute ch c from buf[c&1] while
// writing ch c+1 into buf[(c+1)&1] (data prefetched one iter earlier).
// Counted lgkmcnt(10) = 9 reads done, 10 writes still in flight.
#define PROWS   20
#define TSTRIDE 66
#define TDW     (PROWS * TSTRIDE)    // 1320 dwords = 5280 B per buffer

typedef float f4 __attribute__((ext_vector_type(4)));
typedef _Float16 h2 __attribute__((ext_vector_type(2)));
typedef unsigned u2 __attribute__((ext_vector_type(2)));
typedef unsigned uv2 __attribute__((ext_vector_type(2)));
typedef __attribute__((address_space(3))) unsigned* lup;

static __device__ __forceinline__ unsigned pk(float a, float b) {
    return __builtin_bit_cast(unsigned, __builtin_amdgcn_cvt_pkrtz(a, b));
}
static __device__ __forceinline__ float dot2(unsigned w, unsigned v, float c) {
#if __has_builtin(__builtin_amdgcn_fdot2)
    return __builtin_amdgcn_fdot2(__builtin_bit_cast(h2, w),
                                  __builtin_bit_cast(h2, v), c, false);
#else
    h2 hw = __builtin_bit_cast(h2, w), hv = __builtin_bit_cast(h2, v);
    return c + (float)hw[0] * (float)hv[0] + (float)hw[1] * (float)hv[1];
#endif
}

// Compiler-only memory fence (zero instructions).
#define CFENCE() asm volatile("" ::: "memory")

// One shifted-pipeline iteration. VA = statically-chosen address array
// (va0 for even c, va1 for odd c) -> no runtime-indexed register arrays.
#define PIPE_ITER(cI, VA)                                                   \
  do {                                                                      \
    uv2 pr[Sc];                                                             \
    _Pragma("unroll")                                                       \
    for (int s = 0; s < Sc; ++s)                                            \
      asm volatile("ds_read2_b32 %0, %1 offset0:0 offset1:1"                \
                   : "=v"(pr[s]) : "v"(VA[s]));                             \
    CFENCE();                                                               \
    {                                                                       \
      unsigned* twn = twBase + (((cI) + 1) & 1) * TDW;                      \
      _Pragma("unroll")                                                     \
      for (int j = 0; j < 5; ++j) {                                         \
        unsigned* q = twn + (5 * ls + j) * TSTRIDE + seg * 4;               \
        u2 lo = { pk(rv[j][0], rv[j + 1][0]), pk(rv[j][1], rv[j + 1][1]) }; \
        u2 hi = { pk(rv[j][2], rv[j + 1][2]), pk(rv[j][3], rv[j + 1][3]) }; \
        *(u2*)q       = lo;                                                 \
        *(u2*)(q + 2) = hi;                                                 \
      }                                                                     \
    }                                                                       \
    CFENCE();                                                               \
    float lvN = 0.0f;                                                       \
    if ((cI) + 2 < CPW) {                                                   \
      const float* Rn = Rb + (size_t)((cI) + 2) * HWc;                      \
      _Pragma("unroll")                                                     \
      for (int k = 0; k < 6; ++k) rv[k] = *(const f4*)(Rn + rowEl[k]);      \
      lvN = Lb[(size_t)((cI) + 2) * HWc];                                   \
    }                                                                       \
    asm volatile("s_waitcnt lgkmcnt(10)" ::: "memory");                     \
    __builtin_amdgcn_sched_barrier(0);                                      \
    _Pragma("unroll")                                                       \
    for (int s = 0; s < Sc; ++s) {                                          \
      float sd = dot2(wA[s], pr[s].x, 0.0f);                                \
      sd = dot2(wB[s], pr[s].y, sd);                                        \
      acc[s] = fmaf(lvA, sd, acc[s]);                                       \
    }                                                                       \
    lvA = lvB; lvB = lvN;                                                   \
  } while (0)

__global__ __launch_bounds__(128, 4)
void aoc_corr_kernel(const float* __restrict__ left,
                     const float* __restrict__ right,
                     const float* __restrict__ flow,
                     const float* __restrict__ extra,
                     float* __restrict__ out)
{
    __shared__ unsigned tile[NW][2][TDW];   // 21120 B; reduce buf aliased later

    int bid = blockIdx.x;
    int wt = bid % WTc; bid /= WTc;
    int h2i = bid % H2c; bid /= H2c;
    int g  = bid % Gc;  bid /= Gc;
    int b  = bid;

    const int tid  = threadIdx.x;
    const int wid  = tid >> 6;
    const int lane = tid & 63;
    const int r    = lane >> 5;
    const int col  = lane & 31;
    const int h    = h2i * 2 + r;
    const int w    = wt * 32 + col;
    const int pix  = h * Wc + w;

    const float* flowb = flow + (size_t)b * 2 * HWc;
    const float bx = (float)w + flowb[pix];
    const float by = (float)h + flowb[HWc + pix];

    int   xb9[Sc], y09[Sc], y19[Sc];
    float w00[Sc], w01[Sc], w10[Sc], w11[Sc];
    int minX = 1 << 30, maxX = -(1 << 30), minY = 1 << 30, maxY = -(1 << 30);

    const float* exb = extra + (size_t)b * (2 * Sc) * HWc + pix;
#pragma unroll
    for (int s = 0; s < Sc; ++s) {
        const float ex = exb[(size_t)(2 * s) * HWc];
        const float ey = exb[(size_t)(2 * s + 1) * HWc];
        const float x = bx + (float)(s - 4) + ex;   // window: x offset s-4, y 0
        const float y = by + ey;

        const float x0f = floorf(x);
        const float y0f = floorf(y);
        const float fx = x - x0f;
        const float fy = y - y0f;
        const int x0 = (int)x0f;
        const int y0 = (int)y0f;
        const int y1 = y0 + 1;

        const int xb = min(max(x0, 0), Wc - 2);
        const float cA = (x0 == xb) ? (1.0f - fx) : ((x0 == -1)     ? fx          : 0.0f);
        const float cB = (x0 == xb) ? fx          : ((x0 == Wc - 1) ? (1.0f - fx) : 0.0f);
        const float r0 = (y0 >= 0 && y0 < Hc) ? (1.0f - fy) : 0.0f;
        const float r1 = (y1 >= 0 && y1 < Hc) ? fy          : 0.0f;
        const int yc0 = min(max(y0, 0), Hc - 1);
        const int yc1 = min(max(y1, 0), Hc - 1);

        w00[s] = cA * r0;  w01[s] = cB * r0;
        w10[s] = cA * r1;  w11[s] = cB * r1;
        xb9[s] = xb;  y09[s] = yc0;  y19[s] = yc1;

        minX = min(minX, xb);
        maxX = max(maxX, xb);
        minY = min(minY, min(yc0, yc1));
        maxY = max(maxY, max(yc0, yc1));
    }

    // Wave-wide min/max of the clamped footprint (identical across waves)
#pragma unroll
    for (int k = 1; k < 64; k <<= 1) {
        minX = min(minX, __shfl_xor(minX, k));
        maxX = max(maxX, __shfl_xor(maxX, k));
        minY = min(minY, __shfl_xor(minY, k));
        maxY = max(maxY, __shfl_xor(maxY, k));
    }
    // 16B-aligned 64-wide column window covering [xb, xb+1] for all lanes
    const int minX2 = min(minX, Wc - 64) & ~3;
    const bool valid = (maxY - minY + 1 <= PROWS) && (maxX - minX2 <= 62);

    const float* Rb = right + ((size_t)b * Cc + (size_t)(g * GCc + wid * CPW)) * HWc;
    const float* Lb = left  + ((size_t)b * Cc + (size_t)(g * GCc + wid * CPW)) * HWc + pix;

    float acc[Sc];
#pragma unroll
    for (int s = 0; s < Sc; ++s) acc[s] = 0.0f;

    if (valid) {
        // Weight folding onto the fp16 vertical-pair slots (row identity;
        // handles all clamp cases). Verified passing since R6.
        unsigned wA[Sc], wB[Sc];
        unsigned va0[Sc], va1[Sc];
#pragma unroll
        for (int s = 0; s < Sc; ++s) {
            const int t  = y09[s] - minY;          // 0..PROWS-1 under valid
            const int sB = y19[s] - y09[s];        // 0 or 1
            const float A0 = w00[s] + (sB ? 0.0f : w10[s]);
            const float A1 = sB ? w10[s] : 0.0f;
            const float B0 = w01[s] + (sB ? 0.0f : w11[s]);
            const float B1 = sB ? w11[s] : 0.0f;
            wA[s] = pk(A0, A1);
            wB[s] = pk(B0, B1);
            const int idx = t * TSTRIDE + (xb9[s] - minX2);
            va0[s] = (unsigned)(size_t)(lup)&tile[wid][0][idx];
            va1[s] = va0[s] + TDW * 4;
        }

        // Staging geometry: lane-group ls covers underlying rows
        // [5*ls, 5*ls+5] (6 rows, +1 overlap for vertical pairing).
        const int ls  = lane >> 4;
        const int seg = lane & 15;
        int rowEl[6];
#pragma unroll
        for (int k = 0; k < 6; ++k)
            rowEl[k] = min(minY + 5 * ls + k, Hc - 1) * Wc + minX2 + seg * 4;

        unsigned* twBase = &tile[wid][0][0];

        // Prologue: load ch0 -> regs; write ch0 -> buf0; load ch1 -> regs.
        f4 rv[6];
#pragma unroll
        for (int k = 0; k < 6; ++k) rv[k] = *(const f4*)(Rb + rowEl[k]);
        float lvA = Lb[0];
#pragma unroll
        for (int j = 0; j < 5; ++j) {
            unsigned* q = twBase + (5 * ls + j) * TSTRIDE + seg * 4;
            u2 lo = { pk(rv[j][0], rv[j + 1][0]), pk(rv[j][1], rv[j + 1][1]) };
            u2 hi = { pk(rv[j][2], rv[j + 1][2]), pk(rv[j][3], rv[j + 1][3]) };
            *(u2*)q       = lo;
            *(u2*)(q + 2) = hi;
        }
        CFENCE();
#pragma unroll
        for (int k = 0; k < 6; ++k) rv[k] = *(const f4*)(Rb + HWc + rowEl[k]);
        float lvB = Lb[HWc];

        // Main loop: c = 0..CPW-2, unrolled x2 so buffer selection and the
        // va address arrays are statically indexed. Epilogue handles c=31.
#pragma unroll 1
        for (int cc = 0; cc < CPW - 1; cc += 2) {
            PIPE_ITER(cc, va0);
            if (cc + 1 < CPW - 1) PIPE_ITER(cc + 1, va1);
        }
        // Epilogue: c = CPW-1 (odd -> buf1/va1); no writes outstanding.
        {
            uv2 pr[Sc];
#pragma unroll
            for (int s = 0; s < Sc; ++s)
                asm volatile("ds_read2_b32 %0, %1 offset0:0 offset1:1"
                             : "=v"(pr[s]) : "v"(va1[s]));
            asm volatile("s_waitcnt lgkmcnt(0)" ::: "memory");
            __builtin_amdgcn_sched_barrier(0);
#pragma unroll
            for (int s = 0; s < Sc; ++s) {
                float sd = dot2(wA[s], pr[s].x, 0.0f);
                sd = dot2(wB[s], pr[s].y, sd);
                acc[s] = fmaf(lvA, sd, acc[s]);
            }
        }
    } else {
        // Fallback: direct global gathers, full f32 (footprint outliers)
        int offA[Sc], offB[Sc];
#pragma unroll
        for (int s = 0; s < Sc; ++s) {
            offA[s] = y09[s] * Wc + xb9[s];
            offB[s] = y19[s] * Wc + xb9[s];
        }
        for (int c = 0; c < CPW; ++c) {
            const float lv = Lb[(size_t)c * HWc];
            const float* Rc = Rb + (size_t)c * HWc;
#pragma unroll
            for (int s = 0; s < Sc; ++s) {
                const float vA0 = Rc[offA[s]];
                const float vA1 = Rc[offA[s] + 1];
                const float vB0 = Rc[offB[s]];
                const float vB1 = Rc[offB[s] + 1];
                acc[s] += lv * (w00[s] * vA0 + w01[s] * vA1 +
                                w10[s] * vB0 + w11[s] * vB1);
            }
        }
    }

    // Cross-wave reduction; reduce buffer aliases the dead tile memory.
    float* red = (float*)&tile[0][0][0];   // (NW-1)*Sc*64*4 = 2304 B
    __syncthreads();
    if (wid != 0) {
#pragma unroll
        for (int s = 0; s < Sc; ++s)
            red[((wid - 1) * Sc + s) * 64 + lane] = acc[s];
    }
    __syncthreads();
    if (wid == 0) {
        const float inv = 1.0f / (float)GCc;
        float* ob = out + ((size_t)b * Gc + g) * Sc * HWc + pix;
#pragma unroll
        for (int s = 0; s < Sc; ++s) {
            float v = acc[s];
#pragma unroll
            for (int ww = 1; ww < NW; ++ww)
                v += red[((ww - 1) * Sc + s) * 64 + lane];
            ob[(size_t)s * HWc] = v * inv;
        }
    }
}

extern "C" void kernel_launch(void* const* d_in, const int* in_sizes, int n_in,
                              void* d_out, int out_size, void* d_ws, size_t ws_size,
                              hipStream_t stream) {
    const float* left  = (const float*)d_in[0];
    const float* right = (const float*)d_in[1];
    const float* flow  = (const float*)d_in[2];
    const float* extra = (const float*)d_in[3];
    float* out = (float*)d_out;

    const int nblocks = Bc * Gc * H2c * WTc;  // 2*4*40*5 = 1600
    aoc_corr_kernel<<<nblocks, NW * 64, 0, stream>>>(left, right, flow, extra, out);
}

// Round 10
// 58.428 us; speedup vs baseline: 1.5263x; 1.5263x over previous
//
#include <hip/hip_runtime.h>

// Problem constants (fixed by the reference setup)
#define Bc   2
#define Cc   256
#define Hc   80
#define Wc   160
#define Gc   4
#define Sc   9
#define GCc  64              // channels per group
#define HWc  (Hc * Wc)
#define H2c  (Hc / 2)        // 40 row-pair tiles
#define WTc  (Wc / 32)       // 5 col tiles of 32
#define NW   4               // waves per block
#define CPW  16              // channels per wave

// fp16 vertical-pair tile: dword (t,x) = fp16x2(v(minY+t,x), v(minY+t+1,x)).
// Per-wave DOUBLE buffer (R7-proven): the WAR fence (lgkmcnt(0)) at iter c
// only waits for iter c-2's reads -> free. R10 change vs R7: global prefetch
// distance TWO iterations (rvE/rvO register sets + reload-after-last-use), so
// L2-miss latency (~900cy) is covered; R7 stalled on 1-iter-distance vmcnt.
#define PROWS   20
#define TSTRIDE 66
#define TDW     (PROWS * TSTRIDE)    // 1320 dwords = 5280 B per buffer

typedef float f4 __attribute__((ext_vector_type(4)));
typedef _Float16 h2 __attribute__((ext_vector_type(2)));
typedef unsigned u2 __attribute__((ext_vector_type(2)));

static __device__ __forceinline__ unsigned pk(float a, float b) {
    return __builtin_bit_cast(unsigned, __builtin_amdgcn_cvt_pkrtz(a, b));
}
static __device__ __forceinline__ float dot2(unsigned w, unsigned v, float c) {
#if __has_builtin(__builtin_amdgcn_fdot2)
    return __builtin_amdgcn_fdot2(__builtin_bit_cast(h2, w),
                                  __builtin_bit_cast(h2, v), c, false);
#else
    h2 hw = __builtin_bit_cast(h2, w), hv = __builtin_bit_cast(h2, v);
    return c + (float)hw[0] * (float)hv[0] + (float)hw[1] * (float)hv[1];
#endif
}

// Compiler-only memory fence (zero instructions).
#define CFENCE() asm volatile("" ::: "memory")

// One pipeline iteration, prefetch distance 2. RV/LV are statically-named
// per-parity registers (no runtime indexing). BUF is a compile-time 0/1.
// Order: WAR fence -> write ch c -> CFENCE -> reload RV with ch c+2 ->
// gather+FMA (LV) -> reload LV with left[c+2] AFTER its last use (vmcnt
// wait then lands at iter c+2's FMA, not here).
#define ITER2(cI, RV, LV, BUF)                                              \
  do {                                                                      \
    asm volatile("s_waitcnt lgkmcnt(0)" ::: "memory");                      \
    _Pragma("unroll")                                                       \
    for (int j = 0; j < 5; ++j) {                                           \
      unsigned* q = twBase + (BUF) * TDW + (5 * ls + j) * TSTRIDE + seg * 4;\
      u2 lo = { pk(RV[j][0], RV[j + 1][0]), pk(RV[j][1], RV[j + 1][1]) };   \
      u2 hi = { pk(RV[j][2], RV[j + 1][2]), pk(RV[j][3], RV[j + 1][3]) };   \
      *(u2*)q       = lo;                                                   \
      *(u2*)(q + 2) = hi;                                                   \
    }                                                                       \
    CFENCE();                                                               \
    if ((cI) + 2 < CPW) {                                                   \
      const float* Rn = Rb + (size_t)((cI) + 2) * HWc;                      \
      _Pragma("unroll")                                                     \
      for (int k = 0; k < 6; ++k) RV[k] = *(const f4*)(Rn + rowEl[k]);      \
    }                                                                       \
    {                                                                       \
      const unsigned* twr = twBase + (BUF) * TDW;                           \
      _Pragma("unroll")                                                     \
      for (int s = 0; s < Sc; ++s) {                                        \
        const unsigned d0 = twr[idx[s]];                                    \
        const unsigned d1 = twr[idx[s] + 1];                                \
        float sd = dot2(wA[s], d0, 0.0f);                                   \
        sd = dot2(wB[s], d1, sd);                                           \
        acc[s] = fmaf(LV, sd, acc[s]);                                      \
      }                                                                     \
    }                                                                       \
    if ((cI) + 2 < CPW) LV = Lb[(size_t)((cI) + 2) * HWc];                  \
  } while (0)

__global__ __launch_bounds__(256, 3)
void aoc_corr_kernel(const float* __restrict__ left,
                     const float* __restrict__ right,
                     const float* __restrict__ flow,
                     const float* __restrict__ extra,
                     float* __restrict__ out)
{
    __shared__ unsigned tile[NW][2][TDW];   // 42240 B; reduce buf aliased later

    int bid = blockIdx.x;
    int wt = bid % WTc; bid /= WTc;
    int h2i = bid % H2c; bid /= H2c;
    int g  = bid % Gc;  bid /= Gc;
    int b  = bid;

    const int tid  = threadIdx.x;
    const int wid  = tid >> 6;
    const int lane = tid & 63;
    const int r    = lane >> 5;
    const int col  = lane & 31;
    const int h    = h2i * 2 + r;
    const int w    = wt * 32 + col;
    const int pix  = h * Wc + w;

    const float* flowb = flow + (size_t)b * 2 * HWc;
    const float bx = (float)w + flowb[pix];
    const float by = (float)h + flowb[HWc + pix];

    int   xb9[Sc], y09[Sc], y19[Sc];
    float w00[Sc], w01[Sc], w10[Sc], w11[Sc];
    int minX = 1 << 30, maxX = -(1 << 30), minY = 1 << 30, maxY = -(1 << 30);

    const float* exb = extra + (size_t)b * (2 * Sc) * HWc + pix;
#pragma unroll
    for (int s = 0; s < Sc; ++s) {
        const float ex = exb[(size_t)(2 * s) * HWc];
        const float ey = exb[(size_t)(2 * s + 1) * HWc];
        const float x = bx + (float)(s - 4) + ex;   // window: x offset s-4, y 0
        const float y = by + ey;

        const float x0f = floorf(x);
        const float y0f = floorf(y);
        const float fx = x - x0f;
        const float fy = y - y0f;
        const int x0 = (int)x0f;
        const int y0 = (int)y0f;
        const int y1 = y0 + 1;

        const int xb = min(max(x0, 0), Wc - 2);
        const float cA = (x0 == xb) ? (1.0f - fx) : ((x0 == -1)     ? fx          : 0.0f);
        const float cB = (x0 == xb) ? fx          : ((x0 == Wc - 1) ? (1.0f - fx) : 0.0f);
        const float r0 = (y0 >= 0 && y0 < Hc) ? (1.0f - fy) : 0.0f;
        const float r1 = (y1 >= 0 && y1 < Hc) ? fy          : 0.0f;
        const int yc0 = min(max(y0, 0), Hc - 1);
        const int yc1 = min(max(y1, 0), Hc - 1);

        w00[s] = cA * r0;  w01[s] = cB * r0;
        w10[s] = cA * r1;  w11[s] = cB * r1;
        xb9[s] = xb;  y09[s] = yc0;  y19[s] = yc1;

        minX = min(minX, xb);
        maxX = max(maxX, xb);
        minY = min(minY, min(yc0, yc1));
        maxY = max(maxY, max(yc0, yc1));
    }

    // Wave-wide min/max of the clamped footprint (identical across waves)
#pragma unroll
    for (int k = 1; k < 64; k <<= 1) {
        minX = min(minX, __shfl_xor(minX, k));
        maxX = max(maxX, __shfl_xor(maxX, k));
        minY = min(minY, __shfl_xor(minY, k));
        maxY = max(maxY, __shfl_xor(maxY, k));
    }
    // 16B-aligned 64-wide column window covering [xb, xb+1] for all lanes
    const int minX2 = min(minX, Wc - 64) & ~3;
    const bool valid = (maxY - minY + 1 <= PROWS) && (maxX - minX2 <= 62);

    const float* Rb = right + ((size_t)b * Cc + (size_t)(g * GCc + wid * CPW)) * HWc;
    const float* Lb = left  + ((size_t)b * Cc + (size_t)(g * GCc + wid * CPW)) * HWc + pix;

    float acc[Sc];
#pragma unroll
    for (int s = 0; s < Sc; ++s) acc[s] = 0.0f;

    if (valid) {
        // Per-sample: pair-row t holds rows (y09, y09+1); fold weights onto
        // the two fp16 slots by ROW IDENTITY (handles all clamp cases:
        // y0==-1 -> y09==y19 -> slot0 gets w00+w10; y0==79 -> w10=w11=0).
        unsigned wA[Sc], wB[Sc];
        int idx[Sc];
#pragma unroll
        for (int s = 0; s < Sc; ++s) {
            const int t  = y09[s] - minY;          // 0..PROWS-1 under valid
            const int sB = y19[s] - y09[s];        // 0 or 1
            const float A0 = w00[s] + (sB ? 0.0f : w10[s]);
            const float A1 = sB ? w10[s] : 0.0f;
            const float B0 = w01[s] + (sB ? 0.0f : w11[s]);
            const float B1 = sB ? w11[s] : 0.0f;
            wA[s] = pk(A0, A1);
            wB[s] = pk(B0, B1);
            idx[s] = t * TSTRIDE + (xb9[s] - minX2);
        }

        // Staging geometry: lane-group ls covers underlying rows
        // [5*ls, 5*ls+5] (6 rows, +1 overlap for vertical pairing),
        // 16B col segment seg. 21 underlying rows -> 20 pair-rows.
        const int ls  = lane >> 4;
        const int seg = lane & 15;
        int rowEl[6];
#pragma unroll
        for (int k = 0; k < 6; ++k)
            rowEl[k] = min(minY + 5 * ls + k, Hc - 1) * Wc + minX2 + seg * 4;

        unsigned* twBase = &tile[wid][0][0];

        // Prologue: prefetch channels 0 (even set) and 1 (odd set).
        f4 rvE[6], rvO[6];
#pragma unroll
        for (int k = 0; k < 6; ++k) rvE[k] = *(const f4*)(Rb + rowEl[k]);
#pragma unroll
        for (int k = 0; k < 6; ++k) rvO[k] = *(const f4*)(Rb + HWc + rowEl[k]);
        float lvE = Lb[0];
        float lvO = Lb[HWc];

#pragma unroll 1
        for (int cc = 0; cc < CPW; cc += 2) {
            ITER2(cc,     rvE, lvE, 0);
            ITER2(cc + 1, rvO, lvO, 1);
        }
    } else {
        // Fallback: direct global gathers, full f32 (footprint outliers)
        int offA[Sc], offB[Sc];
#pragma unroll
        for (int s = 0; s < Sc; ++s) {
            offA[s] = y09[s] * Wc + xb9[s];
            offB[s] = y19[s] * Wc + xb9[s];
        }
        for (int c = 0; c < CPW; ++c) {
            const float lv = Lb[(size_t)c * HWc];
            const float* Rc = Rb + (size_t)c * HWc;
#pragma unroll
            for (int s = 0; s < Sc; ++s) {
                const float vA0 = Rc[offA[s]];
                const float vA1 = Rc[offA[s] + 1];
                const float vB0 = Rc[offB[s]];
                const float vB1 = Rc[offB[s] + 1];
                acc[s] += lv * (w00[s] * vA0 + w01[s] * vA1 +
                                w10[s] * vB0 + w11[s] * vB1);
            }
        }
    }

    // 4-way cross-wave reduction; reduce buffer aliases the dead tile memory.
    float* red = (float*)&tile[0][0][0];   // 3*9*64*4 = 6912 B <= 42240 B
    __syncthreads();
    if (wid != 0) {
#pragma unroll
        for (int s = 0; s < Sc; ++s)
            red[((wid - 1) * Sc + s) * 64 + lane] = acc[s];
    }
    __syncthreads();
    if (wid == 0) {
        const float inv = 1.0f / (float)GCc;
        float* ob = out + ((size_t)b * Gc + g) * Sc * HWc + pix;
#pragma unroll
        for (int s = 0; s < Sc; ++s) {
            float v = acc[s];
#pragma unroll
            for (int ww = 1; ww < NW; ++ww)
                v += red[((ww - 1) * Sc + s) * 64 + lane];
            ob[(size_t)s * HWc] = v * inv;
        }
    }
}

extern "C" void kernel_launch(void* const* d_in, const int* in_sizes, int n_in,
                              void* d_out, int out_size, void* d_ws, size_t ws_size,
                              hipStream_t stream) {
    const float* left  = (const float*)d_in[0];
    const float* right = (const float*)d_in[1];
    const float* flow  = (const float*)d_in[2];
    const float* extra = (const float*)d_in[3];
    float* out = (float*)d_out;

    const int nblocks = Bc * Gc * H2c * WTc;  // 2*4*40*5 = 1600
    aoc_corr_kernel<<<nblocks, NW * 64, 0, stream>>>(left, right, flow, extra, out);
}

// Round 11
// 49.706 us; speedup vs baseline: 1.7941x; 1.1755x over previous
//
#include <hip/hip_runtime.h>

// Problem constants (fixed by the reference setup)
#define Bc   2
#define Cc   256
#define Hc   80
#define Wc   160
#define Gc   4
#define Sc   9
#define GCc  64              // channels per group
#define HWc  (Hc * Wc)
#define H2c  (Hc / 2)        // 40 row-pair tiles
#define WTc  (Wc / 32)       // 5 col tiles of 32
#define NW   4               // waves per block
#define CPW  16              // channels per wave

// fp16 vertical-pair tile: dword (t,x) = fp16x2(v(minY+t,x), v(minY+t+1,x)).
// R11: TSTRIDE 68 (16B-aligned rows) + one ds_write_b128 per row-group:
// write quad-bank index (5ls+j+seg)&7 covers each quad-bank with exactly 8
// lanes -> conflict-free writes (R10 had a static 4-way b64-write conflict:
// bank (10ls+4seg+k+2j)&31 collides across ls groups, ~80cy/iter).
// Reads: bank (4t+dx)&31, full 32-bank spread over data-random dx.
#define PROWS   20
#define TSTRIDE 68
#define TDW     (PROWS * TSTRIDE)    // 1360 dwords = 5440 B per buffer

typedef float f4 __attribute__((ext_vector_type(4)));
typedef _Float16 h2 __attribute__((ext_vector_type(2)));
typedef unsigned u4 __attribute__((ext_vector_type(4)));

static __device__ __forceinline__ unsigned pk(float a, float b) {
    return __builtin_bit_cast(unsigned, __builtin_amdgcn_cvt_pkrtz(a, b));
}
static __device__ __forceinline__ float dot2(unsigned w, unsigned v, float c) {
#if __has_builtin(__builtin_amdgcn_fdot2)
    return __builtin_amdgcn_fdot2(__builtin_bit_cast(h2, w),
                                  __builtin_bit_cast(h2, v), c, false);
#else
    h2 hw = __builtin_bit_cast(h2, w), hv = __builtin_bit_cast(h2, v);
    return c + (float)hw[0] * (float)hv[0] + (float)hw[1] * (float)hv[1];
#endif
}

// Compiler-only memory fence (zero instructions).
#define CFENCE() asm volatile("" ::: "memory")

// One pipeline iteration, prefetch distance 2 (R10-proven). RV/LV are
// statically-named per-parity registers. BUF is compile-time 0/1.
#define ITER2(cI, RV, LV, BUF)                                              \
  do {                                                                      \
    asm volatile("s_waitcnt lgkmcnt(0)" ::: "memory");                      \
    _Pragma("unroll")                                                       \
    for (int j = 0; j < 5; ++j) {                                           \
      unsigned* q = twBase + (BUF) * TDW + (5 * ls + j) * TSTRIDE + seg * 4;\
      u4 val = { pk(RV[j][0], RV[j + 1][0]), pk(RV[j][1], RV[j + 1][1]),    \
                 pk(RV[j][2], RV[j + 1][2]), pk(RV[j][3], RV[j + 1][3]) };  \
      *(u4*)q = val;   /* ds_write_b128, conflict-free by construction */   \
    }                                                                       \
    CFENCE();                                                               \
    if ((cI) + 2 < CPW) {                                                   \
      const float* Rn = Rb + (size_t)((cI) + 2) * HWc;                      \
      _Pragma("unroll")                                                     \
      for (int k = 0; k < 6; ++k) RV[k] = *(const f4*)(Rn + rowEl[k]);      \
    }                                                                       \
    {                                                                       \
      const unsigned* twr = twBase + (BUF) * TDW;                           \
      _Pragma("unroll")                                                     \
      for (int s = 0; s < Sc; ++s) {                                        \
        const unsigned d0 = twr[idx[s]];                                    \
        const unsigned d1 = twr[idx[s] + 1];                                \
        float sd = dot2(wA[s], d0, 0.0f);                                   \
        sd = dot2(wB[s], d1, sd);                                           \
        acc[s] = fmaf(LV, sd, acc[s]);                                      \
      }                                                                     \
    }                                                                       \
    if ((cI) + 2 < CPW) LV = Lb[(size_t)((cI) + 2) * HWc];                  \
  } while (0)

__global__ __launch_bounds__(256, 3)
void aoc_corr_kernel(const float* __restrict__ left,
                     const float* __restrict__ right,
                     const float* __restrict__ flow,
                     const float* __restrict__ extra,
                     float* __restrict__ out)
{
    __shared__ unsigned tile[NW][2][TDW];   // 43520 B; reduce buf aliased later

    // XCD chunk swizzle: 1600 blocks = 8 XCDs x 200, and 200 = one (b,g)'s
    // tiles (40 h2 x 5 wt). Round-robin dispatch (p%8 -> XCD) then gives each
    // XCD one full (b,g): its 64-channel right slice (3.3 MB) fits that
    // XCD's 4 MB L2. Bijective for 1600 = 8*200. Perf heuristic only.
    const int p = blockIdx.x;
    int bid = 200 * (p & 7) + (p >> 3);

    int wt = bid % WTc; bid /= WTc;
    int h2i = bid % H2c; bid /= H2c;
    int g  = bid % Gc;  bid /= Gc;
    int b  = bid;

    const int tid  = threadIdx.x;
    const int wid  = tid >> 6;
    const int lane = tid & 63;
    const int r    = lane >> 5;
    const int col  = lane & 31;
    const int h    = h2i * 2 + r;
    const int w    = wt * 32 + col;
    const int pix  = h * Wc + w;

    const float* flowb = flow + (size_t)b * 2 * HWc;
    const float bx = (float)w + flowb[pix];
    const float by = (float)h + flowb[HWc + pix];

    int   xb9[Sc], y09[Sc], y19[Sc];
    float w00[Sc], w01[Sc], w10[Sc], w11[Sc];
    int minX = 1 << 30, maxX = -(1 << 30), minY = 1 << 30, maxY = -(1 << 30);

    const float* exb = extra + (size_t)b * (2 * Sc) * HWc + pix;
#pragma unroll
    for (int s = 0; s < Sc; ++s) {
        const float ex = exb[(size_t)(2 * s) * HWc];
        const float ey = exb[(size_t)(2 * s + 1) * HWc];
        const float x = bx + (float)(s - 4) + ex;   // window: x offset s-4, y 0
        const float y = by + ey;

        const float x0f = floorf(x);
        const float y0f = floorf(y);
        const float fx = x - x0f;
        const float fy = y - y0f;
        const int x0 = (int)x0f;
        const int y0 = (int)y0f;
        const int y1 = y0 + 1;

        const int xb = min(max(x0, 0), Wc - 2);
        const float cA = (x0 == xb) ? (1.0f - fx) : ((x0 == -1)     ? fx          : 0.0f);
        const float cB = (x0 == xb) ? fx          : ((x0 == Wc - 1) ? (1.0f - fx) : 0.0f);
        const float r0 = (y0 >= 0 && y0 < Hc) ? (1.0f - fy) : 0.0f;
        const float r1 = (y1 >= 0 && y1 < Hc) ? fy          : 0.0f;
        const int yc0 = min(max(y0, 0), Hc - 1);
        const int yc1 = min(max(y1, 0), Hc - 1);

        w00[s] = cA * r0;  w01[s] = cB * r0;
        w10[s] = cA * r1;  w11[s] = cB * r1;
        xb9[s] = xb;  y09[s] = yc0;  y19[s] = yc1;

        minX = min(minX, xb);
        maxX = max(maxX, xb);
        minY = min(minY, min(yc0, yc1));
        maxY = max(maxY, max(yc0, yc1));
    }

    // Wave-wide min/max of the clamped footprint (identical across waves)
#pragma unroll
    for (int k = 1; k < 64; k <<= 1) {
        minX = min(minX, __shfl_xor(minX, k));
        maxX = max(maxX, __shfl_xor(maxX, k));
        minY = min(minY, __shfl_xor(minY, k));
        maxY = max(maxY, __shfl_xor(maxY, k));
    }
    // 16B-aligned 64-wide column window covering [xb, xb+1] for all lanes
    const int minX2 = min(minX, Wc - 64) & ~3;
    const bool valid = (maxY - minY + 1 <= PROWS) && (maxX - minX2 <= 62);

    const float* Rb = right + ((size_t)b * Cc + (size_t)(g * GCc + wid * CPW)) * HWc;
    const float* Lb = left  + ((size_t)b * Cc + (size_t)(g * GCc + wid * CPW)) * HWc + pix;

    float acc[Sc];
#pragma unroll
    for (int s = 0; s < Sc; ++s) acc[s] = 0.0f;

    if (valid) {
        // Per-sample: pair-row t holds rows (y09, y09+1); fold weights onto
        // the two fp16 slots by ROW IDENTITY (handles all clamp cases:
        // y0==-1 -> y09==y19 -> slot0 gets w00+w10; y0==79 -> w10=w11=0).
        unsigned wA[Sc], wB[Sc];
        int idx[Sc];
#pragma unroll
        for (int s = 0; s < Sc; ++s) {
            const int t  = y09[s] - minY;          // 0..PROWS-1 under valid
            const int sB = y19[s] - y09[s];        // 0 or 1
            const float A0 = w00[s] + (sB ? 0.0f : w10[s]);
            const float A1 = sB ? w10[s] : 0.0f;
            const float B0 = w01[s] + (sB ? 0.0f : w11[s]);
            const float B1 = sB ? w11[s] : 0.0f;
            wA[s] = pk(A0, A1);
            wB[s] = pk(B0, B1);
            idx[s] = t * TSTRIDE + (xb9[s] - minX2);
        }

        // Staging geometry: lane-group ls covers underlying rows
        // [5*ls, 5*ls+5] (6 rows, +1 overlap for vertical pairing),
        // 16B col segment seg. 21 underlying rows -> 20 pair-rows.
        const int ls  = lane >> 4;
        const int seg = lane & 15;
        int rowEl[6];
#pragma unroll
        for (int k = 0; k < 6; ++k)
            rowEl[k] = min(minY + 5 * ls + k, Hc - 1) * Wc + minX2 + seg * 4;

        unsigned* twBase = &tile[wid][0][0];

        // Prologue: prefetch channels 0 (even set) and 1 (odd set).
        f4 rvE[6], rvO[6];
#pragma unroll
        for (int k = 0; k < 6; ++k) rvE[k] = *(const f4*)(Rb + rowEl[k]);
#pragma unroll
        for (int k = 0; k < 6; ++k) rvO[k] = *(const f4*)(Rb + HWc + rowEl[k]);
        float lvE = Lb[0];
        float lvO = Lb[HWc];

#pragma unroll 1
        for (int cc = 0; cc < CPW; cc += 2) {
            ITER2(cc,     rvE, lvE, 0);
            ITER2(cc + 1, rvO, lvO, 1);
        }
    } else {
        // Fallback: direct global gathers, full f32 (footprint outliers)
        int offA[Sc], offB[Sc];
#pragma unroll
        for (int s = 0; s < Sc; ++s) {
            offA[s] = y09[s] * Wc + xb9[s];
            offB[s] = y19[s] * Wc + xb9[s];
        }
        for (int c = 0; c < CPW; ++c) {
            const float lv = Lb[(size_t)c * HWc];
            const float* Rc = Rb + (size_t)c * HWc;
#pragma unroll
            for (int s = 0; s < Sc; ++s) {
                const float vA0 = Rc[offA[s]];
                const float vA1 = Rc[offA[s] + 1];
                const float vB0 = Rc[offB[s]];
                const float vB1 = Rc[offB[s] + 1];
                acc[s] += lv * (w00[s] * vA0 + w01[s] * vA1 +
                                w10[s] * vB0 + w11[s] * vB1);
            }
        }
    }

    // 4-way cross-wave reduction; reduce buffer aliases the dead tile memory.
    float* red = (float*)&tile[0][0][0];   // 3*9*64*4 = 6912 B <= 43520 B
    __syncthreads();
    if (wid != 0) {
#pragma unroll
        for (int s = 0; s < Sc; ++s)
            red[((wid - 1) * Sc + s) * 64 + lane] = acc[s];
    }
    __syncthreads();
    if (wid == 0) {
        const float inv = 1.0f / (float)GCc;
        float* ob = out + ((size_t)b * Gc + g) * Sc * HWc + pix;
#pragma unroll
        for (int s = 0; s < Sc; ++s) {
            float v = acc[s];
#pragma unroll
            for (int ww = 1; ww < NW; ++ww)
                v += red[((ww - 1) * Sc + s) * 64 + lane];
            ob[(size_t)s * HWc] = v * inv;
        }
    }
}

extern "C" void kernel_launch(void* const* d_in, const int* in_sizes, int n_in,
                              void* d_out, int out_size, void* d_ws, size_t ws_size,
                              hipStream_t stream) {
    const float* left  = (const float*)d_in[0];
    const float* right = (const float*)d_in[1];
    const float* flow  = (const float*)d_in[2];
    const float* extra = (const float*)d_in[3];
    float* out = (float*)d_out;

    const int nblocks = Bc * Gc * H2c * WTc;  // 2*4*40*5 = 1600
    aoc_corr_kernel<<<nblocks, NW * 64, 0, stream>>>(left, right, flow, extra, out);
}

// Round 12
// 47.923 us; speedup vs baseline: 1.8609x; 1.0372x over previous
//
#include <hip/hip_runtime.h>

// Problem constants (fixed by the reference setup)
#define Bc   2
#define Cc   256
#define Hc   80
#define Wc   160
#define Gc   4
#define Sc   9
#define GCc  64              // channels per group
#define HWc  (Hc * Wc)
#define H2c  (Hc / 2)        // 40 row-pair tiles
#define WTc  (Wc / 32)       // 5 col tiles of 32
#define NW   4               // waves per block
#define CPW  16              // channels per wave

// fp16 vertical-pair tile: dword (t,x) = fp16x2(v(minY+t,x), v(minY+t+1,x)).
// TSTRIDE 68: 16B-aligned rows; ds_write_b128 conflict-free by construction
// (R11); read bank (4t+dx)&31 full-spread over data-random dx.
// R12: (a) drop the per-iter s_waitcnt lgkmcnt(0) WAR fence — per-wave DS
// ops execute IN ORDER on the LDS pipe, so ds_write can never pass an
// earlier ds_read; only the zero-cost compiler fence is needed (R6's bug
// was compiler reordering, not HW). The hard fence was retiring 9 in-flight
// gathers (~120cy) every iteration. (b) global prefetch distance 3 (rvA/B/C
// rotation, loop fully unrolled since LCM(2 bufs, 3 sets) = 6 doesn't divide
// 16) — covers the ~900cy HBM-miss latency (~21% of staging misses L2).
#define PROWS   20
#define TSTRIDE 68
#define TDW     (PROWS * TSTRIDE)    // 1360 dwords = 5440 B per buffer

typedef float f4 __attribute__((ext_vector_type(4)));
typedef _Float16 h2 __attribute__((ext_vector_type(2)));
typedef unsigned u4 __attribute__((ext_vector_type(4)));

static __device__ __forceinline__ unsigned pk(float a, float b) {
    return __builtin_bit_cast(unsigned, __builtin_amdgcn_cvt_pkrtz(a, b));
}
static __device__ __forceinline__ float dot2(unsigned w, unsigned v, float c) {
#if __has_builtin(__builtin_amdgcn_fdot2)
    return __builtin_amdgcn_fdot2(__builtin_bit_cast(h2, w),
                                  __builtin_bit_cast(h2, v), c, false);
#else
    h2 hw = __builtin_bit_cast(h2, w), hv = __builtin_bit_cast(h2, v);
    return c + (float)hw[0] * (float)hv[0] + (float)hw[1] * (float)hv[1];
#endif
}

// Compiler-only memory fence (zero instructions).
#define CFENCE() asm volatile("" ::: "memory")

// One pipeline iteration, prefetch distance 3. RV/LV statically named
// (rule #20); BUF compile-time 0/1. No hard lgkm fence: in-order per-wave
// DS pipe makes write-after-read safe; CFENCE pins compiler order.
#define ITER3(cI, RV, LV, BUF)                                              \
  do {                                                                      \
    CFENCE();                                                               \
    _Pragma("unroll")                                                       \
    for (int j = 0; j < 5; ++j) {                                           \
      unsigned* q = twBase + (BUF) * TDW + (5 * ls + j) * TSTRIDE + seg * 4;\
      u4 val = { pk(RV[j][0], RV[j + 1][0]), pk(RV[j][1], RV[j + 1][1]),    \
                 pk(RV[j][2], RV[j + 1][2]), pk(RV[j][3], RV[j + 1][3]) };  \
      *(u4*)q = val;   /* ds_write_b128, conflict-free by construction */   \
    }                                                                       \
    CFENCE();                                                               \
    if ((cI) + 3 < CPW) {                                                   \
      const float* Rn = Rb + (size_t)((cI) + 3) * HWc;                      \
      _Pragma("unroll")                                                     \
      for (int k = 0; k < 6; ++k) RV[k] = *(const f4*)(Rn + rowEl[k]);      \
    }                                                                       \
    {                                                                       \
      const unsigned* twr = twBase + (BUF) * TDW;                           \
      _Pragma("unroll")                                                     \
      for (int s = 0; s < Sc; ++s) {                                        \
        const unsigned d0 = twr[idx[s]];                                    \
        const unsigned d1 = twr[idx[s] + 1];                                \
        float sd = dot2(wA[s], d0, 0.0f);                                   \
        sd = dot2(wB[s], d1, sd);                                           \
        acc[s] = fmaf(LV, sd, acc[s]);                                      \
      }                                                                     \
    }                                                                       \
    if ((cI) + 3 < CPW) LV = Lb[(size_t)((cI) + 3) * HWc];                  \
  } while (0)

__global__ __launch_bounds__(256, 2)
void aoc_corr_kernel(const float* __restrict__ left,
                     const float* __restrict__ right,
                     const float* __restrict__ flow,
                     const float* __restrict__ extra,
                     float* __restrict__ out)
{
    __shared__ unsigned tile[NW][2][TDW];   // 43520 B; reduce buf aliased later

    // XCD chunk swizzle (R11-proven: FETCH 122->30 MB): 1600 = 8 XCDs x 200,
    // and 200 = one (b,g)'s tiles; each XCD keeps one (b,g)'s 3.3 MB
    // right-slice resident in its 4 MB L2. Bijective. Perf heuristic only.
    const int p = blockIdx.x;
    int bid = 200 * (p & 7) + (p >> 3);

    int wt = bid % WTc; bid /= WTc;
    int h2i = bid % H2c; bid /= H2c;
    int g  = bid % Gc;  bid /= Gc;
    int b  = bid;

    const int tid  = threadIdx.x;
    const int wid  = tid >> 6;
    const int lane = tid & 63;
    const int r    = lane >> 5;
    const int col  = lane & 31;
    const int h    = h2i * 2 + r;
    const int w    = wt * 32 + col;
    const int pix  = h * Wc + w;

    const float* flowb = flow + (size_t)b * 2 * HWc;
    const float bx = (float)w + flowb[pix];
    const float by = (float)h + flowb[HWc + pix];

    int   xb9[Sc], y09[Sc], y19[Sc];
    float w00[Sc], w01[Sc], w10[Sc], w11[Sc];
    int minX = 1 << 30, maxX = -(1 << 30), minY = 1 << 30, maxY = -(1 << 30);

    const float* exb = extra + (size_t)b * (2 * Sc) * HWc + pix;
#pragma unroll
    for (int s = 0; s < Sc; ++s) {
        const float ex = exb[(size_t)(2 * s) * HWc];
        const float ey = exb[(size_t)(2 * s + 1) * HWc];
        const float x = bx + (float)(s - 4) + ex;   // window: x offset s-4, y 0
        const float y = by + ey;

        const float x0f = floorf(x);
        const float y0f = floorf(y);
        const float fx = x - x0f;
        const float fy = y - y0f;
        const int x0 = (int)x0f;
        const int y0 = (int)y0f;
        const int y1 = y0 + 1;

        const int xb = min(max(x0, 0), Wc - 2);
        const float cA = (x0 == xb) ? (1.0f - fx) : ((x0 == -1)     ? fx          : 0.0f);
        const float cB = (x0 == xb) ? fx          : ((x0 == Wc - 1) ? (1.0f - fx) : 0.0f);
        const float r0 = (y0 >= 0 && y0 < Hc) ? (1.0f - fy) : 0.0f;
        const float r1 = (y1 >= 0 && y1 < Hc) ? fy          : 0.0f;
        const int yc0 = min(max(y0, 0), Hc - 1);
        const int yc1 = min(max(y1, 0), Hc - 1);

        w00[s] = cA * r0;  w01[s] = cB * r0;
        w10[s] = cA * r1;  w11[s] = cB * r1;
        xb9[s] = xb;  y09[s] = yc0;  y19[s] = yc1;

        minX = min(minX, xb);
        maxX = max(maxX, xb);
        minY = min(minY, min(yc0, yc1));
        maxY = max(maxY, max(yc0, yc1));
    }

    // Wave-wide min/max of the clamped footprint (identical across waves)
#pragma unroll
    for (int k = 1; k < 64; k <<= 1) {
        minX = min(minX, __shfl_xor(minX, k));
        maxX = max(maxX, __shfl_xor(maxX, k));
        minY = min(minY, __shfl_xor(minY, k));
        maxY = max(maxY, __shfl_xor(maxY, k));
    }
    // 16B-aligned 64-wide column window covering [xb, xb+1] for all lanes
    const int minX2 = min(minX, Wc - 64) & ~3;
    const bool valid = (maxY - minY + 1 <= PROWS) && (maxX - minX2 <= 62);

    const float* Rb = right + ((size_t)b * Cc + (size_t)(g * GCc + wid * CPW)) * HWc;
    const float* Lb = left  + ((size_t)b * Cc + (size_t)(g * GCc + wid * CPW)) * HWc + pix;

    float acc[Sc];
#pragma unroll
    for (int s = 0; s < Sc; ++s) acc[s] = 0.0f;

    if (valid) {
        // Per-sample: pair-row t holds rows (y09, y09+1); fold weights onto
        // the two fp16 slots by ROW IDENTITY (handles all clamp cases:
        // y0==-1 -> y09==y19 -> slot0 gets w00+w10; y0==79 -> w10=w11=0).
        unsigned wA[Sc], wB[Sc];
        int idx[Sc];
#pragma unroll
        for (int s = 0; s < Sc; ++s) {
            const int t  = y09[s] - minY;          // 0..PROWS-1 under valid
            const int sB = y19[s] - y09[s];        // 0 or 1
            const float A0 = w00[s] + (sB ? 0.0f : w10[s]);
            const float A1 = sB ? w10[s] : 0.0f;
            const float B0 = w01[s] + (sB ? 0.0f : w11[s]);
            const float B1 = sB ? w11[s] : 0.0f;
            wA[s] = pk(A0, A1);
            wB[s] = pk(B0, B1);
            idx[s] = t * TSTRIDE + (xb9[s] - minX2);
        }

        // Staging geometry: lane-group ls covers underlying rows
        // [5*ls, 5*ls+5] (6 rows, +1 overlap for vertical pairing),
        // 16B col segment seg. 21 underlying rows -> 20 pair-rows.
        const int ls  = lane >> 4;
        const int seg = lane & 15;
        int rowEl[6];
#pragma unroll
        for (int k = 0; k < 6; ++k)
            rowEl[k] = min(minY + 5 * ls + k, Hc - 1) * Wc + minX2 + seg * 4;

        unsigned* twBase = &tile[wid][0][0];

        // Prologue: prefetch channels 0,1,2 into the three register sets.
        f4 rvA[6], rvB[6], rvC[6];
#pragma unroll
        for (int k = 0; k < 6; ++k) rvA[k] = *(const f4*)(Rb + rowEl[k]);
#pragma unroll
        for (int k = 0; k < 6; ++k) rvB[k] = *(const f4*)(Rb + HWc + rowEl[k]);
#pragma unroll
        for (int k = 0; k < 6; ++k) rvC[k] = *(const f4*)(Rb + 2 * HWc + rowEl[k]);
        float lvA = Lb[0];
        float lvB = Lb[HWc];
        float lvC = Lb[2 * (size_t)HWc];

        // Fully unrolled: regset = c % 3, buffer = c & 1 (LCM 6 | pattern).
        ITER3( 0, rvA, lvA, 0);
        ITER3( 1, rvB, lvB, 1);
        ITER3( 2, rvC, lvC, 0);
        ITER3( 3, rvA, lvA, 1);
        ITER3( 4, rvB, lvB, 0);
        ITER3( 5, rvC, lvC, 1);
        ITER3( 6, rvA, lvA, 0);
        ITER3( 7, rvB, lvB, 1);
        ITER3( 8, rvC, lvC, 0);
        ITER3( 9, rvA, lvA, 1);
        ITER3(10, rvB, lvB, 0);
        ITER3(11, rvC, lvC, 1);
        ITER3(12, rvA, lvA, 0);
        ITER3(13, rvB, lvB, 1);
        ITER3(14, rvC, lvC, 0);
        ITER3(15, rvA, lvA, 1);
    } else {
        // Fallback: direct global gathers, full f32 (footprint outliers)
        int offA[Sc], offB[Sc];
#pragma unroll
        for (int s = 0; s < Sc; ++s) {
            offA[s] = y09[s] * Wc + xb9[s];
            offB[s] = y19[s] * Wc + xb9[s];
        }
        for (int c = 0; c < CPW; ++c) {
            const float lv = Lb[(size_t)c * HWc];
            const float* Rc = Rb + (size_t)c * HWc;
#pragma unroll
            for (int s = 0; s < Sc; ++s) {
                const float vA0 = Rc[offA[s]];
                const float vA1 = Rc[offA[s] + 1];
                const float vB0 = Rc[offB[s]];
                const float vB1 = Rc[offB[s] + 1];
                acc[s] += lv * (w00[s] * vA0 + w01[s] * vA1 +
                                w10[s] * vB0 + w11[s] * vB1);
            }
        }
    }

    // 4-way cross-wave reduction; reduce buffer aliases the dead tile memory.
    float* red = (float*)&tile[0][0][0];   // 3*9*64*4 = 6912 B <= 43520 B
    __syncthreads();
    if (wid != 0) {
#pragma unroll
        for (int s = 0; s < Sc; ++s)
            red[((wid - 1) * Sc + s) * 64 + lane] = acc[s];
    }
    __syncthreads();
    if (wid == 0) {
        const float inv = 1.0f / (float)GCc;
        float* ob = out + ((size_t)b * Gc + g) * Sc * HWc + pix;
#pragma unroll
        for (int s = 0; s < Sc; ++s) {
            float v = acc[s];
#pragma unroll
            for (int ww = 1; ww < NW; ++ww)
                v += red[((ww - 1) * Sc + s) * 64 + lane];
            ob[(size_t)s * HWc] = v * inv;
        }
    }
}

extern "C" void kernel_launch(void* const* d_in, const int* in_sizes, int n_in,
                              void* d_out, int out_size, void* d_ws, size_t ws_size,
                              hipStream_t stream) {
    const float* left  = (const float*)d_in[0];
    const float* right = (const float*)d_in[1];
    const float* flow  = (const float*)d_in[2];
    const float* extra = (const float*)d_in[3];
    float* out = (float*)d_out;

    const int nblocks = Bc * Gc * H2c * WTc;  // 2*4*40*5 = 1600
    aoc_corr_kernel<<<nblocks, NW * 64, 0, stream>>>(left, right, flow, extra, out);
}